// Round 5
// baseline (215.184 us; speedup 1.0000x reference)
//
#include <hip/hip_runtime.h>
#include <hip/hip_bf16.h>
#include <stdint.h>

#define N_NODES 20000
#define N_EDGES 640000
#define FEAT 128
#define CAPD 128   // per-dst list cap; deg ~ Poisson(32), P(>128) ~ 1e-43
#define NPHASE 8   // o-feature slices of 16 (2.56 MB h-slice, L2-resident per XCD)

typedef __attribute__((ext_vector_type(8))) short bf16x8;
typedef __attribute__((ext_vector_type(4))) float f32x4;

// ---------- helpers ----------
// packed f32x2 -> bf16x2 (v_cvt_pk_bf16_f32), lo in low half
__device__ __forceinline__ unsigned pkbf16(float lo, float hi) {
  __hip_bfloat162 p = __float22bfloat162_rn(make_float2(lo, hi));
  return *reinterpret_cast<unsigned*>(&p);
}

// order-preserving encode: f32 -> RNE-rounded bf16 -> monotone u16
__device__ __forceinline__ unsigned short enc16(float f) {
  unsigned a = __float_as_uint(f);
  unsigned b = (a + 0x7FFFu + ((a >> 16) & 1u)) >> 16;  // RNE to bf16
  unsigned s = (unsigned)((int)a >> 31);                // 0 or ~0
  return (unsigned short)((b ^ 0x8000u) ^ (s & 0x7FFFu));
}

// inverse of enc16 (result as f32)
__device__ __forceinline__ float dec16(unsigned e) {
  unsigned b = (e & 0x8000u) ? (e ^ 0x8000u) : (e ^ 0xFFFFu);
  return __uint_as_float(b << 16);
}

// packed 2x u16 max
__device__ __forceinline__ void pmax(unsigned& a, unsigned v) {
  asm("v_pk_max_u16 %0, %0, %1" : "+v"(a) : "v"(v));
}

#define PMX4(v)                                              \
  do {                                                       \
    pmax(a0, (v).x); pmax(a1, (v).y);                        \
    pmax(a2, (v).z); pmax(a3, (v).w);                        \
  } while (0)

// ---------- kernel 1: edge scatter (plain per-dst lists) + W -> bf16 ----------
// cnt is pre-zeroed by hipMemsetAsync. First 32 blocks also convert W
// ([o][f] bf16) -- gemm follows in stream order, so Wbf is ready.
__global__ __launch_bounds__(256) void scatter_kernel(const int* __restrict__ ei,
                                                      int* __restrict__ cnt,
                                                      unsigned short* __restrict__ csr,
                                                      const float* __restrict__ W,
                                                      unsigned short* __restrict__ Wbf) {
  int t = blockIdx.x * 256 + threadIdx.x;
  if (t < FEAT * FEAT / 2) {
    float2 w = ((const float2*)W)[t];
    ((unsigned*)Wbf)[t] = pkbf16(w.x, w.y);
  }
  int src = ei[t];
  int dst = ei[N_EDGES + t];
  int pos = atomicAdd(&cnt[dst], 1);
  if (pos < CAPD) csr[(size_t)dst * CAPD + pos] = (unsigned short)src;
}

// ---------- kernel 2: MFMA GEMM + bias -> h (order-preserving u16-encoded) ----------
__global__ __launch_bounds__(256) void gemm_kernel(
    const float4* __restrict__ x, const unsigned short* __restrict__ Wbf,
    const float* __restrict__ b, uint4* __restrict__ h) {
  // x-stage: [t][16 n][136 f] bf16 = 17408 B.  h-stage (aliased): [16 n][520] u16.
  __shared__ __align__(16) unsigned short sm[17408 / 2];
  const int tid = threadIdx.x;
  const int n0 = blockIdx.x * 16;

#pragma unroll
  for (int it = 0; it < 4; ++it) {
    int e = tid + it * 256;       // 16 n x 64 f-pairs
    int n = e >> 6, fp = e & 63;  // f = 2*fp
    float4 a = x[(size_t)(n0 + n) * 128 + 2 * fp];
    float4 c = x[(size_t)(n0 + n) * 128 + 2 * fp + 1];
    ((unsigned*)sm)[(0 * 16 + n) * 68 + fp] = pkbf16(a.x, c.x);
    ((unsigned*)sm)[(1 * 16 + n) * 68 + fp] = pkbf16(a.y, c.y);
    ((unsigned*)sm)[(2 * 16 + n) * 68 + fp] = pkbf16(a.z, c.z);
    ((unsigned*)sm)[(3 * 16 + n) * 68 + fp] = pkbf16(a.w, c.w);
  }

  __syncthreads();

  const int wv = tid >> 6;  // t
  const int l = tid & 63;
  const int col = l & 15;
  const int quad = l >> 4;

  f32x4 acc[8];
#pragma unroll
  for (int os = 0; os < 8; ++os) {
    float bv = b[os * 16 + col];
    acc[os] = (f32x4){bv, bv, bv, bv};
  }

#pragma unroll
  for (int k = 0; k < 4; ++k) {
    bf16x8 af = *(const bf16x8*)&sm[(wv * 16 + col) * 136 + k * 32 + quad * 8];
#pragma unroll
    for (int os = 0; os < 8; ++os) {
      bf16x8 bfv = *(const bf16x8*)&Wbf[(os * 16 + col) * 128 + k * 32 + quad * 8];
      acc[os] = __builtin_amdgcn_mfma_f32_16x16x32_bf16(af, bfv, acc[os], 0, 0, 0);
    }
  }

  __syncthreads();

  // C layout: D[m = quad*4 + r][o = os*16 + col]; h-stage LDS [n][o][t], row 520 u16.
#pragma unroll
  for (int os = 0; os < 8; ++os) {
#pragma unroll
    for (int r = 0; r < 4; ++r) {
      sm[(quad * 4 + r) * 520 + (os * 16 + col) * 4 + wv] = enc16(acc[os][r]);
    }
  }
  __syncthreads();

#pragma unroll
  for (int it = 0; it < 4; ++it) {
    int e = tid + it * 256;
    int n = e >> 6, q = e & 63;
    uint4 v = *(const uint4*)&sm[n * 520 + q * 8];
    h[(size_t)(n0 + n) * 64 + q] = v;
  }
}

// ---------- kernel 3: o-phased max aggregation, 8 dsts per wave ----------
// phase = blockIdx.x & 7 == XCD: 2.56 MB h-slice stays L2-resident per XCD.
// Lane (g = lane>>3, oq = lane&7) owns dst g's 16 B o-slice: NO cross-lane
// reduce, no transposed csr. Per step: 8-lane broadcast u16 index load (L1-hot
// 256 B row) + one 128 B line per dst (8 lines/instr, fully coalesced) +
// 4x v_pk_max_u16. Lanes past their own deg clamp to entry 0 (dup, harmless).
__global__ __launch_bounds__(256) void agg_kernel(
    const uint4* __restrict__ h, const int* __restrict__ cnt,
    const unsigned short* __restrict__ csr, float4* __restrict__ out) {
  const int bid = blockIdx.x;          // 5000 blocks = 625 grp x 8 phases
  const int p = bid & 7;
  const int grp = bid >> 3;
  const int w = threadIdx.x >> 6;
  const int lane = threadIdx.x & 63;
  const int g = lane >> 3;             // dst slot within wave
  const int oq = lane & 7;             // o-pair slot (2 o x 4 t = 16 B)
  const int n = grp * 32 + w * 8 + g;  // this lane's dst

  int deg = cnt[n];
  deg = deg > CAPD ? CAPD : deg;

  const unsigned short* cs = csr + (size_t)n * CAPD;
  int idx0 = (deg > 0) ? (int)cs[0] : 0;  // clamp target (h[0] valid & L1-hot)

  // wave-max of deg (uniform loop bound; lanes past own deg load dups)
  int dmax = deg;
#pragma unroll
  for (int d = 8; d <= 32; d <<= 1) {
    int o = __shfl_xor(dmax, d);
    dmax = o > dmax ? o : dmax;
  }
  dmax = __builtin_amdgcn_readfirstlane(dmax);

  unsigned a0 = 0x007F007Fu, a1 = a0, a2 = a0, a3 = a0;  // enc(-inf) packed
  const char* hb = (const char*)h;
  const unsigned pb = (((unsigned)p * 8 + oq) << 4);  // byte offset within h row

#pragma unroll 2
  for (int j = 0; j < dmax; ++j) {
    int id = (j < deg) ? (int)cs[j] : idx0;
    uint4 v = *(const uint4*)(hb + (((unsigned)id << 10) + pb));
    PMX4(v);
  }

  float4 o0, o1;
  if (deg == 0) {
    o0 = make_float4(0.f, 0.f, 0.f, 0.f);
    o1 = o0;
  } else {
    o0 = make_float4(dec16(a0 & 0xFFFFu), dec16(a0 >> 16),
                     dec16(a1 & 0xFFFFu), dec16(a1 >> 16));
    o1 = make_float4(dec16(a2 & 0xFFFFu), dec16(a2 >> 16),
                     dec16(a3 & 0xFFFFu), dec16(a3 >> 16));
  }
  out[(size_t)n * 128 + p * 16 + oq * 2] = o0;
  out[(size_t)n * 128 + p * 16 + oq * 2 + 1] = o1;
}

// ---------- launcher ----------
extern "C" void kernel_launch(void* const* d_in, const int* in_sizes, int n_in,
                              void* d_out, int out_size, void* d_ws, size_t ws_size,
                              hipStream_t stream) {
  const float* x = (const float*)d_in[0];
  const int* ei = (const int*)d_in[1];
  const float* W = (const float*)d_in[2];
  const float* b = (const float*)d_in[3];
  float* out = (float*)d_out;

  char* ws = (char*)d_ws;
  uint4* h = (uint4*)ws;                                   // 20,480,000 B
  int* cnt = (int*)(ws + 20480000);                        // 20,000 x 4 = 80,000 B
  unsigned short* csr = (unsigned short*)(ws + 20560000);  // 20000*128*2 = 5,120,000 B
  unsigned short* Wbf = (unsigned short*)(ws + 25680000);  // 32,768 B

  hipMemsetAsync(cnt, 0, N_NODES * sizeof(int), stream);
  scatter_kernel<<<N_EDGES / 256, 256, 0, stream>>>(ei, cnt, csr, W, Wbf);
  gemm_kernel<<<N_NODES / 16, 256, 0, stream>>>((const float4*)x, Wbf, b, h);
  agg_kernel<<<(N_NODES / 32) * NPHASE, 256, 0, stream>>>(h, cnt, csr, (float4*)out);
}

// Round 6
// 192.921 us; speedup vs baseline: 1.1154x; 1.1154x over previous
//
#include <hip/hip_runtime.h>
#include <hip/hip_bf16.h>
#include <stdint.h>

#define N_NODES 20000
#define N_EDGES 640000
#define FEAT 128
#define CAPD 128   // per-dst list cap; deg ~ Poisson(32), P(>128) ~ 1e-43
#define NPHASE 8   // o-feature slices of 16 (2.56 MB h-slice, L2-resident per XCD)

typedef __attribute__((ext_vector_type(8))) short bf16x8;
typedef __attribute__((ext_vector_type(4))) float f32x4;

// ---------- helpers ----------
// packed f32x2 -> bf16x2 (v_cvt_pk_bf16_f32), lo in low half
__device__ __forceinline__ unsigned pkbf16(float lo, float hi) {
  __hip_bfloat162 p = __float22bfloat162_rn(make_float2(lo, hi));
  return *reinterpret_cast<unsigned*>(&p);
}

// order-preserving encode: f32 -> RNE-rounded bf16 -> monotone u16
__device__ __forceinline__ unsigned short enc16(float f) {
  unsigned a = __float_as_uint(f);
  unsigned b = (a + 0x7FFFu + ((a >> 16) & 1u)) >> 16;  // RNE to bf16
  unsigned s = (unsigned)((int)a >> 31);                // 0 or ~0
  return (unsigned short)((b ^ 0x8000u) ^ (s & 0x7FFFu));
}

// inverse of enc16 (result as f32)
__device__ __forceinline__ float dec16(unsigned e) {
  unsigned b = (e & 0x8000u) ? (e ^ 0x8000u) : (e ^ 0xFFFFu);
  return __uint_as_float(b << 16);
}

// packed 2x u16 max
__device__ __forceinline__ void pmax(unsigned& a, unsigned v) {
  asm("v_pk_max_u16 %0, %0, %1" : "+v"(a) : "v"(v));
}

#define PMX4(v)                                              \
  do {                                                       \
    pmax(a0, (v).x); pmax(a1, (v).y);                        \
    pmax(a2, (v).z); pmax(a3, (v).w);                        \
  } while (0)

// ---------- kernel 1: edge scatter (plain per-dst lists) + W -> bf16 ----------
// cnt is pre-zeroed by hipMemsetAsync. First 32 blocks also convert W
// ([o][f] bf16) -- gemm follows in stream order, so Wbf is ready.
__global__ __launch_bounds__(256) void scatter_kernel(const int* __restrict__ ei,
                                                      int* __restrict__ cnt,
                                                      unsigned short* __restrict__ csr,
                                                      const float* __restrict__ W,
                                                      unsigned short* __restrict__ Wbf) {
  int t = blockIdx.x * 256 + threadIdx.x;
  if (t < FEAT * FEAT / 2) {
    float2 w = ((const float2*)W)[t];
    ((unsigned*)Wbf)[t] = pkbf16(w.x, w.y);
  }
  int src = ei[t];
  int dst = ei[N_EDGES + t];
  int pos = atomicAdd(&cnt[dst], 1);
  if (pos < CAPD) csr[(size_t)dst * CAPD + pos] = (unsigned short)src;
}

// ---------- kernel 2: MFMA GEMM + bias -> h (order-preserving u16-encoded) ----------
__global__ __launch_bounds__(256) void gemm_kernel(
    const float4* __restrict__ x, const unsigned short* __restrict__ Wbf,
    const float* __restrict__ b, uint4* __restrict__ h) {
  // x-stage: [t][16 n][136 f] bf16 = 17408 B.  h-stage (aliased): [16 n][520] u16.
  __shared__ __align__(16) unsigned short sm[17408 / 2];
  const int tid = threadIdx.x;
  const int n0 = blockIdx.x * 16;

#pragma unroll
  for (int it = 0; it < 4; ++it) {
    int e = tid + it * 256;       // 16 n x 64 f-pairs
    int n = e >> 6, fp = e & 63;  // f = 2*fp
    float4 a = x[(size_t)(n0 + n) * 128 + 2 * fp];
    float4 c = x[(size_t)(n0 + n) * 128 + 2 * fp + 1];
    ((unsigned*)sm)[(0 * 16 + n) * 68 + fp] = pkbf16(a.x, c.x);
    ((unsigned*)sm)[(1 * 16 + n) * 68 + fp] = pkbf16(a.y, c.y);
    ((unsigned*)sm)[(2 * 16 + n) * 68 + fp] = pkbf16(a.z, c.z);
    ((unsigned*)sm)[(3 * 16 + n) * 68 + fp] = pkbf16(a.w, c.w);
  }

  __syncthreads();

  const int wv = tid >> 6;  // t
  const int l = tid & 63;
  const int col = l & 15;
  const int quad = l >> 4;

  f32x4 acc[8];
#pragma unroll
  for (int os = 0; os < 8; ++os) {
    float bv = b[os * 16 + col];
    acc[os] = (f32x4){bv, bv, bv, bv};
  }

#pragma unroll
  for (int k = 0; k < 4; ++k) {
    bf16x8 af = *(const bf16x8*)&sm[(wv * 16 + col) * 136 + k * 32 + quad * 8];
#pragma unroll
    for (int os = 0; os < 8; ++os) {
      bf16x8 bfv = *(const bf16x8*)&Wbf[(os * 16 + col) * 128 + k * 32 + quad * 8];
      acc[os] = __builtin_amdgcn_mfma_f32_16x16x32_bf16(af, bfv, acc[os], 0, 0, 0);
    }
  }

  __syncthreads();

  // C layout: D[m = quad*4 + r][o = os*16 + col]; h-stage LDS [n][o][t], row 520 u16.
#pragma unroll
  for (int os = 0; os < 8; ++os) {
#pragma unroll
    for (int r = 0; r < 4; ++r) {
      sm[(quad * 4 + r) * 520 + (os * 16 + col) * 4 + wv] = enc16(acc[os][r]);
    }
  }
  __syncthreads();

#pragma unroll
  for (int it = 0; it < 4; ++it) {
    int e = tid + it * 256;
    int n = e >> 6, q = e & 63;
    uint4 v = *(const uint4*)&sm[n * 520 + q * 8];
    h[(size_t)(n0 + n) * 64 + q] = v;
  }
}

// ---------- kernel 3: o-phased max aggregation, 8 dsts/wave, LDS-staged idx ----------
// phase = blockIdx.x & 7 == XCD: 2.56 MB h-slice stays L2-resident per XCD.
// Lane (g = lane>>3, oq = lane&7) owns dst g's 16 B o-slice: no cross-lane
// reduce. Indices staged once into LDS (32 rows, coalesced); inner loop
// consumes 8 via ONE ds_read_b128 (group-broadcast, pad 136 => conflict-free)
// and issues 8 INDEPENDENT dwordx4 gathers before the pmax block (ILP-8).
// Lanes past their own deg clamp to entry 0 (L1-hot dup, harmless for max).
__global__ __launch_bounds__(256) void agg_kernel(
    const uint4* __restrict__ h, const int* __restrict__ cnt,
    const unsigned short* __restrict__ csr, float4* __restrict__ out) {
  __shared__ __align__(16) unsigned short sidx[32][136];  // 8704 B, row-padded
  const int bid = blockIdx.x;  // 5000 blocks = 625 grp x 8 phases
  const int p = bid & 7;
  const int grp = bid >> 3;
  const int n0 = grp * 32;
  const int tid = threadIdx.x;

  // stage 32 csr rows -> LDS (each thread copies 2x uint4 = 32 B, coalesced)
  {
    int r = tid >> 3;  // 0..31
    int q = tid & 7;   // 0..7
    const uint4* srow = (const uint4*)(csr + (size_t)(n0 + r) * CAPD);
    *(uint4*)&sidx[r][q * 8] = srow[q];
    *(uint4*)&sidx[r][(q + 8) * 8] = srow[q + 8];
  }
  __syncthreads();

  const int w = tid >> 6;
  const int lane = tid & 63;
  const int g = lane >> 3;             // dst slot within wave
  const int oq = lane & 7;             // o-pair slot (2 o x 4 t = 16 B)
  const int n = n0 + w * 8 + g;        // this lane's dst

  int deg = cnt[n];
  deg = deg > CAPD ? CAPD : deg;

  const unsigned short* myrow = sidx[w * 8 + g];
  int idx0 = (deg > 0) ? (int)myrow[0] : 0;  // clamp target (valid & L1-hot)

  // wave-max of deg (uniform loop bound; clamped lanes load dups)
  int dmax = deg;
#pragma unroll
  for (int d = 8; d <= 32; d <<= 1) {
    int o = __shfl_xor(dmax, d);
    dmax = o > dmax ? o : dmax;
  }
  dmax = __builtin_amdgcn_readfirstlane(dmax);

  unsigned a0 = 0x007F007Fu, a1 = a0, a2 = a0, a3 = a0;  // enc(-inf) packed
  const char* hb = (const char*)h;
  const unsigned pb = (((unsigned)p * 8 + oq) << 4);  // byte offset within h row

  for (int jb = 0; jb < dmax; jb += 8) {
    uint4 iv = *(const uint4*)&myrow[jb];  // ds_read_b128: 8 indices, broadcast
    int e0 = (int)(iv.x & 0xFFFFu), e1 = (int)(iv.x >> 16);
    int e2 = (int)(iv.y & 0xFFFFu), e3 = (int)(iv.y >> 16);
    int e4 = (int)(iv.z & 0xFFFFu), e5 = (int)(iv.z >> 16);
    int e6 = (int)(iv.w & 0xFFFFu), e7 = (int)(iv.w >> 16);
    e0 = (jb + 0 < deg) ? e0 : idx0;
    e1 = (jb + 1 < deg) ? e1 : idx0;
    e2 = (jb + 2 < deg) ? e2 : idx0;
    e3 = (jb + 3 < deg) ? e3 : idx0;
    e4 = (jb + 4 < deg) ? e4 : idx0;
    e5 = (jb + 5 < deg) ? e5 : idx0;
    e6 = (jb + 6 < deg) ? e6 : idx0;
    e7 = (jb + 7 < deg) ? e7 : idx0;
    uint4 v0 = *(const uint4*)(hb + (((unsigned)e0 << 10) + pb));
    uint4 v1 = *(const uint4*)(hb + (((unsigned)e1 << 10) + pb));
    uint4 v2 = *(const uint4*)(hb + (((unsigned)e2 << 10) + pb));
    uint4 v3 = *(const uint4*)(hb + (((unsigned)e3 << 10) + pb));
    uint4 v4 = *(const uint4*)(hb + (((unsigned)e4 << 10) + pb));
    uint4 v5 = *(const uint4*)(hb + (((unsigned)e5 << 10) + pb));
    uint4 v6 = *(const uint4*)(hb + (((unsigned)e6 << 10) + pb));
    uint4 v7 = *(const uint4*)(hb + (((unsigned)e7 << 10) + pb));
    PMX4(v0); PMX4(v1); PMX4(v2); PMX4(v3);
    PMX4(v4); PMX4(v5); PMX4(v6); PMX4(v7);
  }

  float4 o0, o1;
  if (deg == 0) {
    o0 = make_float4(0.f, 0.f, 0.f, 0.f);
    o1 = o0;
  } else {
    o0 = make_float4(dec16(a0 & 0xFFFFu), dec16(a0 >> 16),
                     dec16(a1 & 0xFFFFu), dec16(a1 >> 16));
    o1 = make_float4(dec16(a2 & 0xFFFFu), dec16(a2 >> 16),
                     dec16(a3 & 0xFFFFu), dec16(a3 >> 16));
  }
  out[(size_t)n * 128 + p * 16 + oq * 2] = o0;
  out[(size_t)n * 128 + p * 16 + oq * 2 + 1] = o1;
}

// ---------- launcher ----------
extern "C" void kernel_launch(void* const* d_in, const int* in_sizes, int n_in,
                              void* d_out, int out_size, void* d_ws, size_t ws_size,
                              hipStream_t stream) {
  const float* x = (const float*)d_in[0];
  const int* ei = (const int*)d_in[1];
  const float* W = (const float*)d_in[2];
  const float* b = (const float*)d_in[3];
  float* out = (float*)d_out;

  char* ws = (char*)d_ws;
  uint4* h = (uint4*)ws;                                   // 20,480,000 B
  int* cnt = (int*)(ws + 20480000);                        // 20,000 x 4 = 80,000 B
  unsigned short* csr = (unsigned short*)(ws + 20560000);  // 20000*128*2 = 5,120,000 B
  unsigned short* Wbf = (unsigned short*)(ws + 25680000);  // 32,768 B

  hipMemsetAsync(cnt, 0, N_NODES * sizeof(int), stream);
  scatter_kernel<<<N_EDGES / 256, 256, 0, stream>>>(ei, cnt, csr, W, Wbf);
  gemm_kernel<<<N_NODES / 16, 256, 0, stream>>>((const float4*)x, Wbf, b, h);
  agg_kernel<<<(N_NODES / 32) * NPHASE, 256, 0, stream>>>(h, cnt, csr, (float4*)out);
}